// Round 1
// baseline (104.485 us; speedup 1.0000x reference)
//
#include <hip/hip_runtime.h>

#define D_MODEL 1024
#define D_STATE 16
#define BATCH   2
#define SEQ     2048
#define CHUNK   32
#define NCHUNK  (SEQ / CHUNK)   // 64

// ---------------------------------------------------------------------------
// K1: B_t[b,l,s] = sum_d x[b,l,d] * B_w[s,d]
// Block = 256 threads = 4 waves. Wave w owns s-quad w (s = 4w..4w+3); lane g
// owns d-slice [16g, 16g+16). B_w slice lives in registers (16 float4 = 64
// floats/thread), loaded once per block; rows stream through. Full-d
// reduction is a single in-wave butterfly (no LDS, no syncthreads).
// ---------------------------------------------------------------------------
__global__ __launch_bounds__(256) void k_bt(const float* __restrict__ x,
                                            const float* __restrict__ Bw,
                                            float* __restrict__ bt) {
    const int t    = threadIdx.x;
    const int wave = t >> 6;   // s-quad
    const int lane = t & 63;   // d-group

    float4 bw[4][4];
    const float* bwp = Bw + (wave * 4) * D_MODEL + lane * 16;
#pragma unroll
    for (int i = 0; i < 4; ++i)
#pragma unroll
        for (int k = 0; k < 4; ++k)
            bw[i][k] = *(const float4*)(bwp + i * D_MODEL + k * 4);

    const int ROWS = (BATCH * SEQ) / gridDim.x;
    const int row0 = blockIdx.x * ROWS;
    for (int r = 0; r < ROWS; ++r) {
        const int row = row0 + r;   // flat (b*SEQ + l)
        const float* xr = x + (size_t)row * D_MODEL + lane * 16;
        float4 xv[4];
#pragma unroll
        for (int k = 0; k < 4; ++k) xv[k] = *(const float4*)(xr + k * 4);

        float acc[4] = {0.f, 0.f, 0.f, 0.f};
#pragma unroll
        for (int i = 0; i < 4; ++i) {
#pragma unroll
            for (int k = 0; k < 4; ++k) {
                acc[i] += xv[k].x * bw[i][k].x;
                acc[i] += xv[k].y * bw[i][k].y;
                acc[i] += xv[k].z * bw[i][k].z;
                acc[i] += xv[k].w * bw[i][k].w;
            }
        }
#pragma unroll
        for (int m = 1; m < 64; m <<= 1) {
#pragma unroll
            for (int i = 0; i < 4; ++i) acc[i] += __shfl_xor(acc[i], m, 64);
        }
        if (lane == 0)
            *(float4*)(bt + (size_t)row * D_STATE + wave * 4) =
                make_float4(acc[0], acc[1], acc[2], acc[3]);
    }
}

// ---------------------------------------------------------------------------
// K2: per-chunk local final states (zero-initial scan over CHUNK steps).
// Block = (b, chunk c, d-tile of 16): thread (s = t&15, dd = t>>4).
// f[b][c][d][s] = local final.
// ---------------------------------------------------------------------------
__global__ __launch_bounds__(256) void k_locals(const float* __restrict__ bt,
                                                const float* __restrict__ logA,
                                                float* __restrict__ f) {
    const int blk = blockIdx.x;
    const int dt  = blk & 63;          // D_MODEL/16 = 64 tiles
    const int c   = (blk >> 6) & 63;   // NCHUNK
    const int b   = blk >> 12;

    __shared__ float sbt[CHUNK * D_STATE];   // 2 KB
    const int t = threadIdx.x;
    if (t < (CHUNK * D_STATE) / 4)
        ((float4*)sbt)[t] =
            ((const float4*)(bt + ((size_t)b * SEQ + c * CHUNK) * D_STATE))[t];
    __syncthreads();

    const int s  = t & 15;
    const int dd = t >> 4;
    const int d  = dt * 16 + dd;
    const float A = expf(-expf(logA[d * D_STATE + s]));
    float h = 0.f;
#pragma unroll
    for (int j = 0; j < CHUNK; ++j) h = A * h + sbt[j * D_STATE + s];
    f[(((size_t)b * NCHUNK + c) * D_MODEL + d) * D_STATE + s] = h;
}

// ---------------------------------------------------------------------------
// K3: cross-chunk carry scan, in place over f. One thread per (b,d,s).
// After: f[b][c][d][s] = carry_in for chunk c (state h at l = c*CHUNK - 1).
// ---------------------------------------------------------------------------
__global__ __launch_bounds__(256) void k_carry(const float* __restrict__ logA,
                                               float* __restrict__ f) {
    const int t = blockIdx.x * 256 + threadIdx.x;   // 0..32767
    const int s = t & 15;
    const int d = (t >> 4) & (D_MODEL - 1);
    const int b = t >> 14;
    const float A = expf(-expf(logA[d * D_STATE + s]));
    float AT = A;
#pragma unroll
    for (int i = 0; i < 5; ++i) AT *= AT;   // A^32 = A^CHUNK

    float carry = 0.f;
    const size_t stride = (size_t)D_MODEL * D_STATE;
    size_t idx = (size_t)b * NCHUNK * stride + (size_t)d * D_STATE + s;
    for (int c = 0; c < NCHUNK; ++c) {
        const float fl = f[idx];
        f[idx] = carry;                 // carry_in for chunk c
        carry = AT * carry + fl;        // carry_in for chunk c+1
        idx += stride;
    }
}

// ---------------------------------------------------------------------------
// K4: final pass. Block = (b, chunk c, d-tile of 256); thread = one d.
// Re-run the local scan seeded with carry_in, fuse C-projection + skip,
// write y. x loads / y stores are fully coalesced across the d-tile.
// ---------------------------------------------------------------------------
__global__ __launch_bounds__(256) void k_final(const float* __restrict__ x,
                                               const float* __restrict__ logA,
                                               const float* __restrict__ Cw,
                                               const float* __restrict__ Dv,
                                               const float* __restrict__ bt,
                                               const float* __restrict__ carry,
                                               float* __restrict__ y) {
    const int blk = blockIdx.x;
    const int dt  = blk & 3;           // D_MODEL/256 = 4 tiles
    const int c   = (blk >> 2) & 63;   // NCHUNK
    const int b   = blk >> 8;
    const int t   = threadIdx.x;
    const int d   = dt * 256 + t;

    __shared__ float sbt[CHUNK * D_STATE];   // 2 KB
    if (t < (CHUNK * D_STATE) / 4)
        ((float4*)sbt)[t] =
            ((const float4*)(bt + ((size_t)b * SEQ + c * CHUNK) * D_STATE))[t];
    __syncthreads();

    float A[D_STATE], C[D_STATE], h[D_STATE];
    const float* lp = logA + (size_t)d * D_STATE;
    const float* cp = Cw + (size_t)d * D_STATE;
    const float* hp = carry + (((size_t)b * NCHUNK + c) * D_MODEL + d) * D_STATE;
#pragma unroll
    for (int s = 0; s < D_STATE; ++s) {
        A[s] = expf(-expf(lp[s]));
        C[s] = cp[s];
        h[s] = hp[s];
    }
    const float dv = Dv[d];

    const size_t rowbase = ((size_t)b * SEQ + c * CHUNK) * D_MODEL + d;
    const float* xp = x + rowbase;
    float*       yp = y + rowbase;

#pragma unroll 4
    for (int j = 0; j < CHUNK; ++j) {
        float acc = dv * xp[(size_t)j * D_MODEL];
#pragma unroll
        for (int s = 0; s < D_STATE; ++s) {
            h[s] = A[s] * h[s] + sbt[j * D_STATE + s];
            acc += C[s] * h[s];
        }
        yp[(size_t)j * D_MODEL] = acc;
    }
}

extern "C" void kernel_launch(void* const* d_in, const int* in_sizes, int n_in,
                              void* d_out, int out_size, void* d_ws, size_t ws_size,
                              hipStream_t stream) {
    const float* x    = (const float*)d_in[0];
    const float* logA = (const float*)d_in[1];
    const float* Bw   = (const float*)d_in[2];
    const float* Cw   = (const float*)d_in[3];
    const float* Dv   = (const float*)d_in[4];
    float* y = (float*)d_out;

    float* bt = (float*)d_ws;                                  // B*L*S   = 65536 floats
    float* f  = bt + (size_t)BATCH * SEQ * D_STATE;            // B*Nc*D*S = 2097152 floats

    hipLaunchKernelGGL(k_bt,     dim3(512),  dim3(256), 0, stream, x, Bw, bt);
    hipLaunchKernelGGL(k_locals, dim3(BATCH * NCHUNK * (D_MODEL / 16)),  dim3(256), 0, stream, bt, logA, f);
    hipLaunchKernelGGL(k_carry,  dim3((BATCH * D_MODEL * D_STATE) / 256), dim3(256), 0, stream, logA, f);
    hipLaunchKernelGGL(k_final,  dim3(BATCH * NCHUNK * (D_MODEL / 256)),  dim3(256), 0, stream, x, logA, Cw, Dv, bt, f, y);
}